// Round 4
// baseline (10735.942 us; speedup 1.0000x reference)
//
#include <hip/hip_runtime.h>
#include <hip/hip_bf16.h>
#include <math.h>

#define T_LEN 128

// Dtype-agnostic scalar load: IS32 ? f32 : bf16 (bit-shift convert, exact).
template<bool IS32>
__device__ __forceinline__ float LD(const void* p, size_t i) {
    if (IS32) return ((const float*)p)[i];
    unsigned int u = ((const unsigned short*)p)[i];
    union { unsigned int ui; float f; } v; v.ui = u << 16; return v.f;
}

// Dtype-matched store.
template<bool IS32>
__device__ __forceinline__ void ST(void* p, size_t i, float x) {
    if (IS32) ((float*)p)[i] = x;
    else      ((__bf16*)p)[i] = (__bf16)x;
}

// Decide whether the float inputs are f32 or bf16 by inspecting EVEN 16-bit
// words of eps (~N(0,1)). If the buffer is bf16, word 2k is a genuine bf16
// value: exponent field in [64,134] essentially always. If the buffer is f32
// (little-endian), word 2k is the LOW mantissa half of float k: uniform bits,
// "sane" with p~=0.28. 512 samples -> >25 sigma separation at threshold 384.
__global__ void detect_kernel(const unsigned short* __restrict__ eps_raw,
                              int* __restrict__ flag) {
    if (blockIdx.x == 0 && threadIdx.x == 0) {
        int sane = 0;
        for (int k = 0; k < 512; ++k) {
            unsigned short w = eps_raw[2 * k];
            int e = (w >> 7) & 0xFF;
            if (w == 0 || (e >= 64 && e <= 134)) ++sane;
        }
        flag[0] = (sane >= 384) ? 0 : 1;   // many sane -> bf16 (IS32=0) else f32
    }
}

struct SM {
    float zx[4][40];    // x = [a(8) | z(32)]
    float h[4][256];
    float u1[4][128];
    float u2[4][128];
    float zz[4][64];
};

template<bool IS32>
__device__ void run_seq(SM* sm, int n0,
    const void* A, const void* eps, const void* z0, const void* h0, const void* c0,
    const void* Wih, const void* Whh, const void* bih, const void* bhh,
    const void* W1, const void* b1, const void* W2, const void* b2,
    const void* Wz, const void* bz, void* __restrict__ out)
{
    const int tid = threadIdx.x;

    // ---- init state (f32 everywhere; h,c never round-trip through bf16)
    if (tid < 128) {                       // z part: 4 rows x 32
        int rr = tid >> 5, cc = tid & 31;
        sm->zx[rr][8 + cc] = LD<IS32>(z0, cc);
    }
    for (int i = tid; i < 4 * 256; i += 256)
        sm->h[i >> 8][i & 255] = LD<IS32>(h0, i & 255);
    float c[4];
    #pragma unroll
    for (int rr = 0; rr < 4; ++rr) c[rr] = LD<IS32>(c0, tid);

    float gbias[4];
    #pragma unroll
    for (int g = 0; g < 4; ++g)
        gbias[g] = LD<IS32>(bih, g * 256 + tid) + LD<IS32>(bhh, g * 256 + tid);

    for (int t = 0; t < T_LEN; ++t) {
        // ---- stage a_t
        if (tid < 32) {
            int rr = tid >> 3, cc = tid & 7;
            sm->zx[rr][cc] = LD<IS32>(A, ((size_t)(n0 + rr) * T_LEN + t) * 8 + cc);
        }
        __syncthreads();   // orders a-writes, prev z-writes, init writes

        // ---- gates: thread tid owns LSTM unit tid of each gate, all 4 rows
        float acc[4][4];   // [gate][row]
        #pragma unroll
        for (int g = 0; g < 4; ++g)
            #pragma unroll
            for (int rr = 0; rr < 4; ++rr) acc[g][rr] = gbias[g];

        for (int k = 0; k < 40; ++k) {
            float xv[4];
            #pragma unroll
            for (int rr = 0; rr < 4; ++rr) xv[rr] = sm->zx[rr][k];
            #pragma unroll
            for (int g = 0; g < 4; ++g) {
                float w = LD<IS32>(Wih, (size_t)(g * 256 + tid) * 40 + k);
                #pragma unroll
                for (int rr = 0; rr < 4; ++rr) acc[g][rr] += w * xv[rr];
            }
        }
        for (int k = 0; k < 256; ++k) {
            float hv[4];
            #pragma unroll
            for (int rr = 0; rr < 4; ++rr) hv[rr] = sm->h[rr][k];
            #pragma unroll
            for (int g = 0; g < 4; ++g) {
                float w = LD<IS32>(Whh, (size_t)(g * 256 + tid) * 256 + k);
                #pragma unroll
                for (int rr = 0; rr < 4; ++rr) acc[g][rr] += w * hv[rr];
            }
        }
        __syncthreads();   // all threads done READING h before h is rewritten

        // ---- LSTM cell (unit tid, rows 0..3); c in registers
        #pragma unroll
        for (int rr = 0; rr < 4; ++rr) {
            float iv = 1.0f / (1.0f + expf(-acc[0][rr]));
            float fv = 1.0f / (1.0f + expf(-acc[1][rr]));
            float gv = tanhf(acc[2][rr]);
            float ov = 1.0f / (1.0f + expf(-acc[3][rr]));
            float cn = fv * c[rr] + iv * gv;
            c[rr] = cn;
            sm->h[rr][tid] = ov * tanhf(cn);
        }
        __syncthreads();

        // ---- u1 = relu(h @ W1^T + b1): col = tid&127, row pair = (tid>>7)*2
        {
            int col = tid & 127, rb = (tid >> 7) * 2;
            float a0 = LD<IS32>(b1, col), a1 = a0;
            for (int k = 0; k < 256; ++k) {
                float w = LD<IS32>(W1, (size_t)col * 256 + k);
                a0 += w * sm->h[rb][k];
                a1 += w * sm->h[rb + 1][k];
            }
            sm->u1[rb][col]     = fmaxf(a0, 0.0f);
            sm->u1[rb + 1][col] = fmaxf(a1, 0.0f);
        }
        __syncthreads();

        // ---- u2 = relu(u1 @ W2^T + b2)
        {
            int col = tid & 127, rb = (tid >> 7) * 2;
            float a0 = LD<IS32>(b2, col), a1 = a0;
            for (int k = 0; k < 128; ++k) {
                float w = LD<IS32>(W2, (size_t)col * 128 + k);
                a0 += w * sm->u1[rb][k];
                a1 += w * sm->u1[rb + 1][k];
            }
            sm->u2[rb][col]     = fmaxf(a0, 0.0f);
            sm->u2[rb + 1][col] = fmaxf(a1, 0.0f);
        }
        __syncthreads();

        // ---- zz = u2 @ Wz^T + bz: rr = tid>>6, col = tid&63
        {
            int rr = tid >> 6, col = tid & 63;
            float a0 = LD<IS32>(bz, col);
            for (int k = 0; k < 128; ++k)
                a0 += LD<IS32>(Wz, (size_t)col * 128 + k) * sm->u2[rr][k];
            sm->zz[rr][col] = a0;
        }
        __syncthreads();

        // ---- z = loc + softplus(raw) * eps; feed back + write out (dtype-matched)
        if (tid < 128) {
            int rr = tid >> 5, cc = tid & 31;
            float loc = sm->zz[rr][cc];
            float raw = sm->zz[rr][cc + 32];
            float sp  = (raw > 20.0f) ? raw : log1pf(expf(raw));
            float ev  = LD<IS32>(eps, ((size_t)(n0 + rr) * T_LEN + t) * 32 + cc);
            float zv  = loc + sp * ev;
            sm->zx[rr][8 + cc] = zv;
            ST<IS32>(out, ((size_t)(n0 + rr) * T_LEN + t) * 32 + cc, zv);
        }
        __syncthreads();   // z visible before next gates read
    }
}

__global__ __launch_bounds__(256) void seq_valu(
    const int* __restrict__ flag,
    const void* A, const void* eps, const void* z0, const void* h0, const void* c0,
    const void* Wih, const void* Whh, const void* bih, const void* bhh,
    const void* W1, const void* b1, const void* W2, const void* b2,
    const void* Wz, const void* bz, void* out)
{
    __shared__ SM sm;
    int n0 = blockIdx.x * 4;
    if (flag[0])
        run_seq<true >(&sm, n0, A, eps, z0, h0, c0, Wih, Whh, bih, bhh,
                       W1, b1, W2, b2, Wz, bz, out);
    else
        run_seq<false>(&sm, n0, A, eps, z0, h0, c0, Wih, Whh, bih, bhh,
                       W1, b1, W2, b2, Wz, bz, out);
}

extern "C" void kernel_launch(void* const* d_in, const int* in_sizes, int n_in,
                              void* d_out, int out_size, void* d_ws, size_t ws_size,
                              hipStream_t stream)
{
    detect_kernel<<<1, 64, 0, stream>>>((const unsigned short*)d_in[1], (int*)d_ws);
    seq_valu<<<256, 256, 0, stream>>>(
        (const int*)d_ws,
        d_in[0], d_in[1], d_in[2], d_in[3], d_in[4],
        d_in[5], d_in[6], d_in[7], d_in[8],
        d_in[9], d_in[10], d_in[11], d_in[12],
        d_in[13], d_in[14], d_out);
}

// Round 5
// 2779.079 us; speedup vs baseline: 3.8631x; 3.8631x over previous
//
#include <hip/hip_runtime.h>
#include <hip/hip_bf16.h>
#include <math.h>

typedef __bf16 bf16x8 __attribute__((ext_vector_type(8)));
typedef float floatx4 __attribute__((ext_vector_type(4)));

#define T_LEN 128
#define KC 2                       // gates k-iters register-cached per wave

// ws layout: bf16 fragment-packed weights
#define WP_OFF   0
#define WP_SZ    (64*10*64*16)     // gates: 64 ct x 10 ki x 64 lanes x 16B = 655360
#define W1P_OFF  (WP_OFF + WP_SZ)
#define W1P_SZ   (8*8*64*16)       // 65536
#define W2P_OFF  (W1P_OFF + W1P_SZ)
#define W2P_SZ   (8*4*64*16)       // 32768
#define WZP_OFF  (W2P_OFF + W2P_SZ)
#define WZP_SZ   (4*4*64*16)       // 16384
#define WS_NEEDED ((size_t)(WZP_OFF + WZP_SZ))   // 770048 B

// ---------------- prep: f32 weights -> bf16 B-fragment-linear in ws -------
// B-frag for mfma_f32_16x16x32_bf16: lane holds B[k=(lane>>4)*8+j][n=lane&15].
// Fragment (ct,ki) lives at ((ct*KI+ki)*64+lane)*8 bf16 elements.
__global__ void prep_kernel(const float* __restrict__ Wih, const float* __restrict__ Whh,
                            const float* __restrict__ W1,  const float* __restrict__ W2,
                            const float* __restrict__ Wz,  unsigned char* __restrict__ ws)
{
    int id = blockIdx.x * blockDim.x + threadIdx.x;
    __bf16* Wp  = (__bf16*)(ws + WP_OFF);
    __bf16* W1p = (__bf16*)(ws + W1P_OFF);
    __bf16* W2p = (__bf16*)(ws + W2P_OFF);
    __bf16* Wzp = (__bf16*)(ws + WZP_OFF);
    if (id < 40960) {                       // gates: 64 ct x 10 ki x 64 lanes
        int rem = id % 640, lane = rem % 64;
        int row = (id / 640) * 16 + (lane & 15);         // gate-output col
        int kb  = (rem / 64) * 32 + (lane >> 4) * 8;
        for (int j = 0; j < 8; ++j) {
            int k = kb + j;
            float v;
            if (k < 40)       v = Wih[row * 40 + k];
            else if (k < 296) v = Whh[row * 256 + (k - 40)];
            else              v = 0.0f;                   // K-pad 296..319
            Wp[(size_t)id * 8 + j] = (__bf16)v;
        }
    } else if (id < 45056) {                // W1: 8 ct x 8 ki
        int id2 = id - 40960;
        int rem = id2 % 512, lane = rem % 64;
        int row = (id2 / 512) * 16 + (lane & 15);
        int kb  = (rem / 64) * 32 + (lane >> 4) * 8;
        for (int j = 0; j < 8; ++j) W1p[(size_t)id2 * 8 + j] = (__bf16)W1[row * 256 + kb + j];
    } else if (id < 47104) {                // W2: 8 ct x 4 ki
        int id3 = id - 45056;
        int rem = id3 % 256, lane = rem % 64;
        int row = (id3 / 256) * 16 + (lane & 15);
        int kb  = (rem / 64) * 32 + (lane >> 4) * 8;
        for (int j = 0; j < 8; ++j) W2p[(size_t)id3 * 8 + j] = (__bf16)W2[row * 128 + kb + j];
    } else if (id < 48128) {                // Wz: 4 ct x 4 ki
        int id4 = id - 47104;
        int rem = id4 % 256, lane = rem % 64;
        int row = (id4 / 256) * 16 + (lane & 15);
        int kb  = (rem / 64) * 32 + (lane >> 4) * 8;
        for (int j = 0; j < 8; ++j) Wzp[(size_t)id4 * 8 + j] = (__bf16)Wz[row * 128 + kb + j];
    }
}

// ---------------- fast path: 64 blocks x 1024 threads, 16 rows/block ------
__global__ __launch_bounds__(1024) void seq_mfma(
    const float* __restrict__ A,   const float* __restrict__ eps,
    const float* __restrict__ z0,  const float* __restrict__ h0,
    const float* __restrict__ c0,
    const float* __restrict__ bih, const float* __restrict__ bhh,
    const float* __restrict__ b1,  const float* __restrict__ b2,
    const float* __restrict__ bz,
    const unsigned char* __restrict__ ws, float* __restrict__ out)
{
    const int tid  = threadIdx.x;
    const int wave = tid >> 6;       // 0..15 = unit-tile owned
    const int lane = tid & 63;
    const int lrow = lane & 15;
    const int quad = lane >> 4;
    const int n0   = blockIdx.x * 16;

    // x = [a(8)|z(32)|h(256)|pad(24)]; row = 656B = 41x16 (ds_read_b128-aligned)
    __shared__ __align__(16) __bf16 xh[16][328];
    __shared__ __align__(16) __bf16 u1s[16][136];
    __shared__ __align__(16) __bf16 u2s[16][136];
    __shared__ __align__(16) float  zzs[16][68];

    const int unit = wave * 16 + lrow;           // within-gate output col

    // streamed-fragment base pointers (per-lane)
    const char* gbase[4];
    #pragma unroll
    for (int g = 0; g < 4; ++g)
        gbase[g] = (const char*)ws + WP_OFF + ((size_t)((g * 16 + wave) * 10) * 64 + lane) * 16;
    const char* u1base = (const char*)ws + W1P_OFF + ((size_t)((wave & 7) * 8) * 64 + lane) * 16;
    const char* u2base = (const char*)ws + W2P_OFF + ((size_t)((wave & 7) * 4) * 64 + lane) * 16;
    const char* uzbase = (const char*)ws + WZP_OFF + ((size_t)((wave & 3) * 4) * 64 + lane) * 16;

    // register-cache first KC gates k-iters (4 frags each)
    bf16x8 wc[4][KC];
    #pragma unroll
    for (int g = 0; g < 4; ++g)
        #pragma unroll
        for (int ki = 0; ki < KC; ++ki)
            wc[g][ki] = *(const bf16x8*)(gbase[g] + ki * 1024);

    float gb[4];
    #pragma unroll
    for (int g = 0; g < 4; ++g)
        gb[g] = bih[g * 256 + unit] + bhh[g * 256 + unit];
    float u1b = b1[(wave & 7) * 16 + lrow];
    float u2b = b2[(wave & 7) * 16 + lrow];
    float zzb = bz[(wave & 3) * 16 + lrow];

    // c-state fp32 in registers, C/D layout (row=quad*4+r, col=unit)
    float cst[4];
    {
        float cv = c0[unit];
        #pragma unroll
        for (int r = 0; r < 4; ++r) cst[r] = cv;
    }

    // init z/h/pad of xh
    for (int idx = tid; idx < 16 * 320; idx += 1024) {
        int r = idx / 320, col = 8 + idx % 320;
        float v;
        if (col < 40)       v = z0[col - 8];
        else if (col < 296) v = h0[col - 40];
        else                v = 0.0f;
        xh[r][col] = (__bf16)v;
    }

    for (int t = 0; t < T_LEN; ++t) {
        // ---- stage a_t (f32 -> bf16)
        if (tid < 128) {
            int r = tid >> 3, c = tid & 7;
            xh[r][c] = (__bf16)A[((size_t)(n0 + r) * T_LEN + t) * 8 + c];
        }
        __syncthreads();   // also orders prev-step z writes + init writes

        // ---- gates: wave owns unit-tile `wave`: cts {g*16+wave}
        floatx4 acc[4];
        #pragma unroll
        for (int g = 0; g < 4; ++g)
            acc[g] = (floatx4){gb[g], gb[g], gb[g], gb[g]};
        #pragma unroll
        for (int ki = 0; ki < 10; ++ki) {
            bf16x8 a = *(const bf16x8*)&xh[lrow][ki * 32 + quad * 8];
            #pragma unroll
            for (int g = 0; g < 4; ++g) {
                bf16x8 b = (ki < KC) ? wc[g][ki]
                                     : *(const bf16x8*)(gbase[g] + ki * 1024);
                acc[g] = __builtin_amdgcn_mfma_f32_16x16x32_bf16(a, b, acc[g], 0, 0, 0);
            }
        }
        __syncthreads();   // xh (a,z,h) reads complete

        // ---- LSTM cell: acc[0..3] = i,f,g,o for (row=quad*4+r, col=unit)
        #pragma unroll
        for (int r = 0; r < 4; ++r) {
            float iv = 1.0f / (1.0f + expf(-acc[0][r]));
            float fv = 1.0f / (1.0f + expf(-acc[1][r]));
            float gv = tanhf(acc[2][r]);
            float ov = 1.0f / (1.0f + expf(-acc[3][r]));
            float cn = fv * cst[r] + iv * gv;
            cst[r] = cn;
            xh[quad * 4 + r][40 + unit] = (__bf16)(ov * tanhf(cn));
        }
        __syncthreads();

        // ---- u1 = relu(h @ W1^T + b1): waves 0..7, ct = wave
        if (wave < 8) {
            floatx4 a1 = (floatx4){u1b, u1b, u1b, u1b};
            #pragma unroll
            for (int ki = 0; ki < 8; ++ki) {
                bf16x8 a = *(const bf16x8*)&xh[lrow][40 + ki * 32 + quad * 8];
                bf16x8 b = *(const bf16x8*)(u1base + ki * 1024);
                a1 = __builtin_amdgcn_mfma_f32_16x16x32_bf16(a, b, a1, 0, 0, 0);
            }
            #pragma unroll
            for (int r = 0; r < 4; ++r)
                u1s[quad * 4 + r][wave * 16 + lrow] = (__bf16)fmaxf(a1[r], 0.0f);
        }
        __syncthreads();

        // ---- u2 = relu(u1 @ W2^T + b2): waves 0..7
        if (wave < 8) {
            floatx4 a2 = (floatx4){u2b, u2b, u2b, u2b};
            #pragma unroll
            for (int ki = 0; ki < 4; ++ki) {
                bf16x8 a = *(const bf16x8*)&u1s[lrow][ki * 32 + quad * 8];
                bf16x8 b = *(const bf16x8*)(u2base + ki * 1024);
                a2 = __builtin_amdgcn_mfma_f32_16x16x32_bf16(a, b, a2, 0, 0, 0);
            }
            #pragma unroll
            for (int r = 0; r < 4; ++r)
                u2s[quad * 4 + r][wave * 16 + lrow] = (__bf16)fmaxf(a2[r], 0.0f);
        }
        __syncthreads();

        // ---- zz = u2 @ Wz^T + bz: waves 0..3
        if (wave < 4) {
            floatx4 a3 = (floatx4){zzb, zzb, zzb, zzb};
            #pragma unroll
            for (int ki = 0; ki < 4; ++ki) {
                bf16x8 a = *(const bf16x8*)&u2s[lrow][ki * 32 + quad * 8];
                bf16x8 b = *(const bf16x8*)(uzbase + ki * 1024);
                a3 = __builtin_amdgcn_mfma_f32_16x16x32_bf16(a, b, a3, 0, 0, 0);
            }
            #pragma unroll
            for (int r = 0; r < 4; ++r)
                zzs[quad * 4 + r][wave * 16 + lrow] = a3[r];
        }
        __syncthreads();

        // ---- z = loc + softplus(raw)*eps; f32 out + bf16 feedback
        if (tid < 512) {
            int r = tid >> 5, c = tid & 31;
            float loc = zzs[r][c];
            float raw = zzs[r][c + 32];
            float sp  = (raw > 20.0f) ? raw : log1pf(expf(raw));
            float ev  = eps[((size_t)(n0 + r) * T_LEN + t) * 32 + c];
            float zv  = loc + sp * ev;
            xh[r][8 + c] = (__bf16)zv;
            out[((size_t)(n0 + r) * T_LEN + t) * 32 + c] = zv;
        }
        // z writes (cols 8..39) vs next a-stage (cols 0..7) disjoint;
        // next post-a-stage barrier orders z before gates reads.
    }
}

// ---------------- fallback: proven R4 VALU kernel (f32 hard-coded) --------
struct SM {
    float zx[4][40]; float h[4][256]; float u1[4][128]; float u2[4][128]; float zz[4][64];
};

__global__ __launch_bounds__(256) void seq_valu(
    const float* __restrict__ A, const float* __restrict__ eps,
    const float* __restrict__ z0, const float* __restrict__ h0, const float* __restrict__ c0,
    const float* __restrict__ Wih, const float* __restrict__ Whh,
    const float* __restrict__ bih, const float* __restrict__ bhh,
    const float* __restrict__ W1, const float* __restrict__ b1,
    const float* __restrict__ W2, const float* __restrict__ b2,
    const float* __restrict__ Wz, const float* __restrict__ bz, float* __restrict__ out)
{
    __shared__ SM sm;
    const int tid = threadIdx.x;
    const int n0  = blockIdx.x * 4;
    if (tid < 128) { int rr = tid >> 5, cc = tid & 31; sm.zx[rr][8 + cc] = z0[cc]; }
    for (int i = tid; i < 4 * 256; i += 256) sm.h[i >> 8][i & 255] = h0[i & 255];
    float c[4];
    #pragma unroll
    for (int rr = 0; rr < 4; ++rr) c[rr] = c0[tid];
    float gbias[4];
    #pragma unroll
    for (int g = 0; g < 4; ++g) gbias[g] = bih[g * 256 + tid] + bhh[g * 256 + tid];

    for (int t = 0; t < T_LEN; ++t) {
        if (tid < 32) { int rr = tid >> 3, cc = tid & 7;
            sm.zx[rr][cc] = A[((size_t)(n0 + rr) * T_LEN + t) * 8 + cc]; }
        __syncthreads();
        float acc[4][4];
        #pragma unroll
        for (int g = 0; g < 4; ++g)
            #pragma unroll
            for (int rr = 0; rr < 4; ++rr) acc[g][rr] = gbias[g];
        for (int k = 0; k < 40; ++k) {
            float xv[4];
            #pragma unroll
            for (int rr = 0; rr < 4; ++rr) xv[rr] = sm.zx[rr][k];
            #pragma unroll
            for (int g = 0; g < 4; ++g) {
                float w = Wih[(size_t)(g * 256 + tid) * 40 + k];
                #pragma unroll
                for (int rr = 0; rr < 4; ++rr) acc[g][rr] += w * xv[rr];
            }
        }
        for (int k = 0; k < 256; ++k) {
            float hv[4];
            #pragma unroll
            for (int rr = 0; rr < 4; ++rr) hv[rr] = sm.h[rr][k];
            #pragma unroll
            for (int g = 0; g < 4; ++g) {
                float w = Whh[(size_t)(g * 256 + tid) * 256 + k];
                #pragma unroll
                for (int rr = 0; rr < 4; ++rr) acc[g][rr] += w * hv[rr];
            }
        }
        __syncthreads();
        #pragma unroll
        for (int rr = 0; rr < 4; ++rr) {
            float iv = 1.0f / (1.0f + expf(-acc[0][rr]));
            float fv = 1.0f / (1.0f + expf(-acc[1][rr]));
            float gv = tanhf(acc[2][rr]);
            float ov = 1.0f / (1.0f + expf(-acc[3][rr]));
            float cn = fv * c[rr] + iv * gv;
            c[rr] = cn;
            sm.h[rr][tid] = ov * tanhf(cn);
        }
        __syncthreads();
        { int col = tid & 127, rb = (tid >> 7) * 2;
          float a0 = b1[col], a1 = a0;
          for (int k = 0; k < 256; ++k) { float w = W1[(size_t)col * 256 + k];
              a0 += w * sm.h[rb][k]; a1 += w * sm.h[rb + 1][k]; }
          sm.u1[rb][col] = fmaxf(a0, 0.0f); sm.u1[rb + 1][col] = fmaxf(a1, 0.0f); }
        __syncthreads();
        { int col = tid & 127, rb = (tid >> 7) * 2;
          float a0 = b2[col], a1 = a0;
          for (int k = 0; k < 128; ++k) { float w = W2[(size_t)col * 128 + k];
              a0 += w * sm.u1[rb][k]; a1 += w * sm.u1[rb + 1][k]; }
          sm.u2[rb][col] = fmaxf(a0, 0.0f); sm.u2[rb + 1][col] = fmaxf(a1, 0.0f); }
        __syncthreads();
        { int rr = tid >> 6, col = tid & 63;
          float a0 = bz[col];
          for (int k = 0; k < 128; ++k) a0 += Wz[(size_t)col * 128 + k] * sm.u2[rr][k];
          sm.zz[rr][col] = a0; }
        __syncthreads();
        if (tid < 128) {
            int rr = tid >> 5, cc = tid & 31;
            float loc = sm.zz[rr][cc], raw = sm.zz[rr][cc + 32];
            float sp  = (raw > 20.0f) ? raw : log1pf(expf(raw));
            float ev  = eps[((size_t)(n0 + rr) * T_LEN + t) * 32 + cc];
            float zv  = loc + sp * ev;
            sm.zx[rr][8 + cc] = zv;
            out[((size_t)(n0 + rr) * T_LEN + t) * 32 + cc] = zv;
        }
        __syncthreads();
    }
}

extern "C" void kernel_launch(void* const* d_in, const int* in_sizes, int n_in,
                              void* d_out, int out_size, void* d_ws, size_t ws_size,
                              hipStream_t stream)
{
    const float* A   = (const float*)d_in[0];
    const float* eps = (const float*)d_in[1];
    const float* z0  = (const float*)d_in[2];
    const float* h0  = (const float*)d_in[3];
    const float* c0  = (const float*)d_in[4];
    const float* Wih = (const float*)d_in[5];
    const float* Whh = (const float*)d_in[6];
    const float* bih = (const float*)d_in[7];
    const float* bhh = (const float*)d_in[8];
    const float* W1  = (const float*)d_in[9];
    const float* b1  = (const float*)d_in[10];
    const float* W2  = (const float*)d_in[11];
    const float* b2  = (const float*)d_in[12];
    const float* Wz  = (const float*)d_in[13];
    const float* bz  = (const float*)d_in[14];
    float* out = (float*)d_out;

    if (ws_size >= WS_NEEDED) {
        prep_kernel<<<188, 256, 0, stream>>>(Wih, Whh, W1, W2, Wz, (unsigned char*)d_ws);
        seq_mfma<<<64, 1024, 0, stream>>>(A, eps, z0, h0, c0,
                                          bih, bhh, b1, b2, bz,
                                          (const unsigned char*)d_ws, out);
    } else {
        seq_valu<<<256, 256, 0, stream>>>(A, eps, z0, h0, c0, Wih, Whh, bih, bhh,
                                          W1, b1, W2, b2, Wz, bz, out);
    }
}

// Round 6
// 2450.170 us; speedup vs baseline: 4.3817x; 1.1342x over previous
//
#include <hip/hip_runtime.h>
#include <hip/hip_bf16.h>
#include <math.h>

typedef __bf16 bf16x8 __attribute__((ext_vector_type(8)));
typedef float floatx4 __attribute__((ext_vector_type(4)));
typedef unsigned int uint4v __attribute__((ext_vector_type(4)));

#define T_LEN 128

// ws layout: bf16 fragment-packed weights (unchanged from R5)
#define WP_OFF   0
#define WP_SZ    (64*10*64*16)     // gates: 64 ct x 10 ki x 64 lanes x 16B = 655360
#define W1P_OFF  (WP_OFF + WP_SZ)
#define W1P_SZ   (8*8*64*16)       // 65536
#define W2P_OFF  (W1P_OFF + W1P_SZ)
#define W2P_SZ   (8*4*64*16)       // 32768
#define WZP_OFF  (W2P_OFF + W2P_SZ)
#define WZP_SZ   (4*4*64*16)       // 16384
#define WS_NEEDED ((size_t)(WZP_OFF + WZP_SZ))   // 770048 B
#define MLP_BYTES (W1P_SZ + W2P_SZ + WZP_SZ)     // 114688 B
#define MLP_ELEM  (MLP_BYTES / 2)                // 57344 bf16
#define U2_EOFF   (W1P_SZ / 2)                   // 32768 elem
#define WZ_EOFF   ((W1P_SZ + W2P_SZ) / 2)        // 49152 elem

// ---------------- prep: f32 weights -> bf16 B-fragment-linear in ws -------
// B-frag for mfma_f32_16x16x32_bf16: lane holds B[k=(lane>>4)*8+j][n=lane&15].
// Fragment (ct,ki) lives at ((ct*KI+ki)*64+lane)*8 bf16 elements.
__global__ void prep_kernel(const float* __restrict__ Wih, const float* __restrict__ Whh,
                            const float* __restrict__ W1,  const float* __restrict__ W2,
                            const float* __restrict__ Wz,  unsigned char* __restrict__ ws)
{
    int id = blockIdx.x * blockDim.x + threadIdx.x;
    __bf16* Wp  = (__bf16*)(ws + WP_OFF);
    __bf16* W1p = (__bf16*)(ws + W1P_OFF);
    __bf16* W2p = (__bf16*)(ws + W2P_OFF);
    __bf16* Wzp = (__bf16*)(ws + WZP_OFF);
    if (id < 40960) {                       // gates: 64 ct x 10 ki x 64 lanes
        int rem = id % 640, lane = rem % 64;
        int row = (id / 640) * 16 + (lane & 15);         // gate-output col
        int kb  = (rem / 64) * 32 + (lane >> 4) * 8;
        for (int j = 0; j < 8; ++j) {
            int k = kb + j;
            float v;
            if (k < 40)       v = Wih[row * 40 + k];
            else if (k < 296) v = Whh[row * 256 + (k - 40)];
            else              v = 0.0f;                   // K-pad 296..319
            Wp[(size_t)id * 8 + j] = (__bf16)v;
        }
    } else if (id < 45056) {                // W1: 8 ct x 8 ki
        int id2 = id - 40960;
        int rem = id2 % 512, lane = rem % 64;
        int row = (id2 / 512) * 16 + (lane & 15);
        int kb  = (rem / 64) * 32 + (lane >> 4) * 8;
        for (int j = 0; j < 8; ++j) W1p[(size_t)id2 * 8 + j] = (__bf16)W1[row * 256 + kb + j];
    } else if (id < 47104) {                // W2: 8 ct x 4 ki
        int id3 = id - 45056;
        int rem = id3 % 256, lane = rem % 64;
        int row = (id3 / 256) * 16 + (lane & 15);
        int kb  = (rem / 64) * 32 + (lane >> 4) * 8;
        for (int j = 0; j < 8; ++j) W2p[(size_t)id3 * 8 + j] = (__bf16)W2[row * 128 + kb + j];
    } else if (id < 48128) {                // Wz: 4 ct x 4 ki
        int id4 = id - 47104;
        int rem = id4 % 256, lane = rem % 64;
        int row = (id4 / 256) * 16 + (lane & 15);
        int kb  = (rem / 64) * 32 + (lane >> 4) * 8;
        for (int j = 0; j < 8; ++j) Wzp[(size_t)id4 * 8 + j] = (__bf16)Wz[row * 128 + kb + j];
    }
}

// ---------------- fast path: 64 blocks x 1024 threads, 16 rows/block ------
// Gates weights live in each wave's registers (40 frags = 160 VGPRs);
// MLP weights live in LDS (112 KB); A/eps prefetched into registers.
// Zero global weight traffic inside the T-loop.
__global__ __launch_bounds__(1024) void seq_mfma(
    const float* __restrict__ A,   const float* __restrict__ eps,
    const float* __restrict__ z0,  const float* __restrict__ h0,
    const float* __restrict__ c0,
    const float* __restrict__ bih, const float* __restrict__ bhh,
    const float* __restrict__ b1,  const float* __restrict__ b2,
    const float* __restrict__ bz,
    const unsigned char* __restrict__ ws, float* __restrict__ out)
{
    const int tid  = threadIdx.x;
    const int wave = tid >> 6;
    const int lane = tid & 63;
    const int lrow = lane & 15;
    const int quad = lane >> 4;
    const int n0   = blockIdx.x * 16;

    __shared__ __align__(16) __bf16 xh[16][328];   // [a(8)|z(32)|h(256)|pad(24)]
    __shared__ __align__(16) __bf16 u1s[16][136];
    __shared__ __align__(16) __bf16 u2s[16][136];
    __shared__ __align__(16) float  zzs[16][68];
    __shared__ __align__(16) __bf16 mlpw[MLP_ELEM];  // W1P|W2P|WZP verbatim

    // ---- one-time: MLP weights -> LDS (coalesced 16B copies)
    {
        const uint4v* src = (const uint4v*)(ws + W1P_OFF);
        uint4v* dst = (uint4v*)mlpw;
        #pragma unroll
        for (int i = 0; i < MLP_BYTES / 16 / 1024; ++i)
            dst[i * 1024 + tid] = src[i * 1024 + tid];
    }

    // ---- one-time: gates fragments -> registers (40 frags/wave)
    const char* gbase[4];
    #pragma unroll
    for (int g = 0; g < 4; ++g)
        gbase[g] = (const char*)ws + WP_OFF + ((size_t)((g * 16 + wave) * 10) * 64 + lane) * 16;
    bf16x8 wg[10][4];
    #pragma unroll
    for (int ki = 0; ki < 10; ++ki)
        #pragma unroll
        for (int g = 0; g < 4; ++g)
            wg[ki][g] = *(const bf16x8*)(gbase[g] + ki * 1024);

    const int unit = wave * 16 + lrow;
    float gb[4];
    #pragma unroll
    for (int g = 0; g < 4; ++g)
        gb[g] = bih[g * 256 + unit] + bhh[g * 256 + unit];
    float u1b = b1[(wave & 7) * 16 + lrow];
    float u2b = b2[(wave & 7) * 16 + lrow];
    float zzb = bz[(wave & 3) * 16 + lrow];

    float cst[4];
    {
        float cv = c0[unit];
        #pragma unroll
        for (int r = 0; r < 4; ++r) cst[r] = cv;
    }

    // init z/h/pad of xh
    for (int idx = tid; idx < 16 * 320; idx += 1024) {
        int r = idx / 320, col = 8 + idx % 320;
        float v;
        if (col < 40)       v = z0[col - 8];
        else if (col < 296) v = h0[col - 40];
        else                v = 0.0f;
        xh[r][col] = (__bf16)v;
    }

    // prefetch a(t=0)
    float a_cur = 0.0f;
    if (tid < 128)
        a_cur = A[((size_t)(n0 + (tid >> 3)) * T_LEN + 0) * 8 + (tid & 7)];

    for (int t = 0; t < T_LEN; ++t) {
        // ---- stage a_t from prefetch register
        if (tid < 128)
            xh[tid >> 3][tid & 7] = (__bf16)a_cur;
        __syncthreads();   // orders a-stage, prev z writes, init writes, mlpw copy

        // ---- early-issue prefetches (consumed ~2-4K cycles later)
        float eps_cur = 0.0f;
        if (tid < 512)
            eps_cur = eps[((size_t)(n0 + (tid >> 5)) * T_LEN + t) * 32 + (tid & 31)];
        float a_nxt = 0.0f;
        if (t + 1 < T_LEN && tid < 128)
            a_nxt = A[((size_t)(n0 + (tid >> 3)) * T_LEN + (t + 1)) * 8 + (tid & 7)];

        // ---- gates: pure LDS A-frags + register B-frags
        floatx4 acc[4];
        #pragma unroll
        for (int g = 0; g < 4; ++g)
            acc[g] = (floatx4){gb[g], gb[g], gb[g], gb[g]};
        #pragma unroll
        for (int ki = 0; ki < 10; ++ki) {
            bf16x8 a = *(const bf16x8*)&xh[lrow][ki * 32 + quad * 8];
            #pragma unroll
            for (int g = 0; g < 4; ++g)
                acc[g] = __builtin_amdgcn_mfma_f32_16x16x32_bf16(a, wg[ki][g], acc[g], 0, 0, 0);
        }
        __syncthreads();   // xh (a,z,h) reads complete

        // ---- LSTM cell: acc[0..3] = i,f,g,o for (row=quad*4+r, col=unit)
        #pragma unroll
        for (int r = 0; r < 4; ++r) {
            float iv = 1.0f / (1.0f + expf(-acc[0][r]));
            float fv = 1.0f / (1.0f + expf(-acc[1][r]));
            float gv = tanhf(acc[2][r]);
            float ov = 1.0f / (1.0f + expf(-acc[3][r]));
            float cn = fv * cst[r] + iv * gv;
            cst[r] = cn;
            xh[quad * 4 + r][40 + unit] = (__bf16)(ov * tanhf(cn));
        }
        __syncthreads();

        // ---- u1 = relu(h @ W1^T + b1): waves 0..7, weights from LDS
        if (wave < 8) {
            floatx4 a1 = (floatx4){u1b, u1b, u1b, u1b};
            #pragma unroll
            for (int ki = 0; ki < 8; ++ki) {
                bf16x8 a = *(const bf16x8*)&xh[lrow][40 + ki * 32 + quad * 8];
                bf16x8 b = *(const bf16x8*)&mlpw[(((wave & 7) * 8 + ki) * 64 + lane) * 8];
                a1 = __builtin_amdgcn_mfma_f32_16x16x32_bf16(a, b, a1, 0, 0, 0);
            }
            #pragma unroll
            for (int r = 0; r < 4; ++r)
                u1s[quad * 4 + r][wave * 16 + lrow] = (__bf16)fmaxf(a1[r], 0.0f);
        }
        __syncthreads();

        // ---- u2 = relu(u1 @ W2^T + b2): waves 0..7
        if (wave < 8) {
            floatx4 a2 = (floatx4){u2b, u2b, u2b, u2b};
            #pragma unroll
            for (int ki = 0; ki < 4; ++ki) {
                bf16x8 a = *(const bf16x8*)&u1s[lrow][ki * 32 + quad * 8];
                bf16x8 b = *(const bf16x8*)&mlpw[U2_EOFF + (((wave & 7) * 4 + ki) * 64 + lane) * 8];
                a2 = __builtin_amdgcn_mfma_f32_16x16x32_bf16(a, b, a2, 0, 0, 0);
            }
            #pragma unroll
            for (int r = 0; r < 4; ++r)
                u2s[quad * 4 + r][wave * 16 + lrow] = (__bf16)fmaxf(a2[r], 0.0f);
        }
        __syncthreads();

        // ---- zz = u2 @ Wz^T + bz: waves 0..3
        if (wave < 4) {
            floatx4 a3 = (floatx4){zzb, zzb, zzb, zzb};
            #pragma unroll
            for (int ki = 0; ki < 4; ++ki) {
                bf16x8 a = *(const bf16x8*)&u2s[lrow][ki * 32 + quad * 8];
                bf16x8 b = *(const bf16x8*)&mlpw[WZ_EOFF + (((wave & 3) * 4 + ki) * 64 + lane) * 8];
                a3 = __builtin_amdgcn_mfma_f32_16x16x32_bf16(a, b, a3, 0, 0, 0);
            }
            #pragma unroll
            for (int r = 0; r < 4; ++r)
                zzs[quad * 4 + r][wave * 16 + lrow] = a3[r];
        }
        __syncthreads();

        // ---- z = loc + softplus(raw)*eps (prefetched); f32 out + bf16 feedback
        if (tid < 512) {
            int r = tid >> 5, c = tid & 31;
            float loc = zzs[r][c];
            float raw = zzs[r][c + 32];
            float sp  = (raw > 20.0f) ? raw : log1pf(expf(raw));
            float zv  = loc + sp * eps_cur;
            xh[r][8 + c] = (__bf16)zv;
            out[((size_t)(n0 + r) * T_LEN + t) * 32 + c] = zv;
        }
        a_cur = a_nxt;
        // z writes (cols 8..39) vs next a-stage (cols 0..7) disjoint;
        // next post-a-stage barrier orders z before gates reads.
    }
}

// ---------------- fallback: proven R4 VALU kernel (f32 hard-coded) --------
struct SM {
    float zx[4][40]; float h[4][256]; float u1[4][128]; float u2[4][128]; float zz[4][64];
};

__global__ __launch_bounds__(256) void seq_valu(
    const float* __restrict__ A, const float* __restrict__ eps,
    const float* __restrict__ z0, const float* __restrict__ h0, const float* __restrict__ c0,
    const float* __restrict__ Wih, const float* __restrict__ Whh,
    const float* __restrict__ bih, const float* __restrict__ bhh,
    const float* __restrict__ W1, const float* __restrict__ b1,
    const float* __restrict__ W2, const float* __restrict__ b2,
    const float* __restrict__ Wz, const float* __restrict__ bz, float* __restrict__ out)
{
    __shared__ SM sm;
    const int tid = threadIdx.x;
    const int n0  = blockIdx.x * 4;
    if (tid < 128) { int rr = tid >> 5, cc = tid & 31; sm.zx[rr][8 + cc] = z0[cc]; }
    for (int i = tid; i < 4 * 256; i += 256) sm.h[i >> 8][i & 255] = h0[i & 255];
    float c[4];
    #pragma unroll
    for (int rr = 0; rr < 4; ++rr) c[rr] = c0[tid];
    float gbias[4];
    #pragma unroll
    for (int g = 0; g < 4; ++g) gbias[g] = bih[g * 256 + tid] + bhh[g * 256 + tid];

    for (int t = 0; t < T_LEN; ++t) {
        if (tid < 32) { int rr = tid >> 3, cc = tid & 7;
            sm.zx[rr][cc] = A[((size_t)(n0 + rr) * T_LEN + t) * 8 + cc]; }
        __syncthreads();
        float acc[4][4];
        #pragma unroll
        for (int g = 0; g < 4; ++g)
            #pragma unroll
            for (int rr = 0; rr < 4; ++rr) acc[g][rr] = gbias[g];
        for (int k = 0; k < 40; ++k) {
            float xv[4];
            #pragma unroll
            for (int rr = 0; rr < 4; ++rr) xv[rr] = sm.zx[rr][k];
            #pragma unroll
            for (int g = 0; g < 4; ++g) {
                float w = Wih[(size_t)(g * 256 + tid) * 40 + k];
                #pragma unroll
                for (int rr = 0; rr < 4; ++rr) acc[g][rr] += w * xv[rr];
            }
        }
        for (int k = 0; k < 256; ++k) {
            float hv[4];
            #pragma unroll
            for (int rr = 0; rr < 4; ++rr) hv[rr] = sm.h[rr][k];
            #pragma unroll
            for (int g = 0; g < 4; ++g) {
                float w = Whh[(size_t)(g * 256 + tid) * 256 + k];
                #pragma unroll
                for (int rr = 0; rr < 4; ++rr) acc[g][rr] += w * hv[rr];
            }
        }
        __syncthreads();
        #pragma unroll
        for (int rr = 0; rr < 4; ++rr) {
            float iv = 1.0f / (1.0f + expf(-acc[0][rr]));
            float fv = 1.0f / (1.0f + expf(-acc[1][rr]));
            float gv = tanhf(acc[2][rr]);
            float ov = 1.0f / (1.0f + expf(-acc[3][rr]));
            float cn = fv * c[rr] + iv * gv;
            c[rr] = cn;
            sm.h[rr][tid] = ov * tanhf(cn);
        }
        __syncthreads();
        { int col = tid & 127, rb = (tid >> 7) * 2;
          float a0 = b1[col], a1 = a0;
          for (int k = 0; k < 256; ++k) { float w = W1[(size_t)col * 256 + k];
              a0 += w * sm.h[rb][k]; a1 += w * sm.h[rb + 1][k]; }
          sm.u1[rb][col] = fmaxf(a0, 0.0f); sm.u1[rb + 1][col] = fmaxf(a1, 0.0f); }
        __syncthreads();
        { int col = tid & 127, rb = (tid >> 7) * 2;
          float a0 = b2[col], a1 = a0;
          for (int k = 0; k < 128; ++k) { float w = W2[(size_t)col * 128 + k];
              a0 += w * sm.u1[rb][k]; a1 += w * sm.u1[rb + 1][k]; }
          sm.u2[rb][col] = fmaxf(a0, 0.0f); sm.u2[rb + 1][col] = fmaxf(a1, 0.0f); }
        __syncthreads();
        { int rr = tid >> 6, col = tid & 63;
          float a0 = bz[col];
          for (int k = 0; k < 128; ++k) a0 += Wz[(size_t)col * 128 + k] * sm.u2[rr][k];
          sm.zz[rr][col] = a0; }
        __syncthreads();
        if (tid < 128) {
            int rr = tid >> 5, cc = tid & 31;
            float loc = sm.zz[rr][cc], raw = sm.zz[rr][cc + 32];
            float sp  = (raw > 20.0f) ? raw : log1pf(expf(raw));
            float ev  = eps[((size_t)(n0 + rr) * T_LEN + t) * 32 + cc];
            float zv  = loc + sp * ev;
            sm.zx[rr][8 + cc] = zv;
            out[((size_t)(n0 + rr) * T_LEN + t) * 32 + cc] = zv;
        }
        __syncthreads();
    }
}

extern "C" void kernel_launch(void* const* d_in, const int* in_sizes, int n_in,
                              void* d_out, int out_size, void* d_ws, size_t ws_size,
                              hipStream_t stream)
{
    const float* A   = (const float*)d_in[0];
    const float* eps = (const float*)d_in[1];
    const float* z0  = (const float*)d_in[2];
    const float* h0  = (const float*)d_in[3];
    const float* c0  = (const float*)d_in[4];
    const float* Wih = (const float*)d_in[5];
    const float* Whh = (const float*)d_in[6];
    const float* bih = (const float*)d_in[7];
    const float* bhh = (const float*)d_in[8];
    const float* W1  = (const float*)d_in[9];
    const float* b1  = (const float*)d_in[10];
    const float* W2  = (const float*)d_in[11];
    const float* b2  = (const float*)d_in[12];
    const float* Wz  = (const float*)d_in[13];
    const float* bz  = (const float*)d_in[14];
    float* out = (float*)d_out;

    if (ws_size >= WS_NEEDED) {
        prep_kernel<<<188, 256, 0, stream>>>(Wih, Whh, W1, W2, Wz, (unsigned char*)d_ws);
        seq_mfma<<<64, 1024, 0, stream>>>(A, eps, z0, h0, c0,
                                          bih, bhh, b1, b2, bz,
                                          (const unsigned char*)d_ws, out);
    } else {
        seq_valu<<<256, 256, 0, stream>>>(A, eps, z0, h0, c0, Wih, Whh, bih, bhh,
                                          W1, b1, W2, b2, Wz, bz, out);
    }
}